// Round 2
// baseline (1230.519 us; speedup 1.0000x reference)
//
#include <hip/hip_runtime.h>
#include <hip/hip_bf16.h>
#include <cstdint>
#include <cstddef>

// Problem constants (B=batch, P=patches, C=channels/d_model)
#define BB 1024
#define PP 64
#define CC 512

constexpr int CT = 8;    // channels per block (1 per wave, 8 waves)
constexpr int BT = 64;   // batches per block (1 per lane)
constexpr float LN_EPS = 1e-5f;

// ---------------- LDS map (50176 B total, kept < 64 KiB) ----------------
// Phase A (x staging, one p-half at a time):
//   ushort xs[CT][BT][40]   (32 valid p + 8 pad; rows 80 B, 16 B aligned) = 40960 B
// Phase B (after xr regs loaded; overlaps/reuses the same memory):
//   float ssum[64q][64b] @ 0      (16384 B)
//   float ssq [64q][64b] @ 16384  (16384 B)
//   float R   [64b][68]  @ 32768  (17408 B)  res-staging, 8-q chunks, pad 68 breaks bank alias

__device__ __forceinline__ float bf2f(unsigned short h) {
    union { unsigned int u; float f; } v; v.u = ((unsigned int)h) << 16; return v.f;
}
__device__ __forceinline__ unsigned short f2bf(float f) {
    union { float f; unsigned int u; } v; v.f = f;
    unsigned int r = v.u + 0x7fffu + ((v.u >> 16) & 1u);   // RNE, inputs finite
    return (unsigned short)(r >> 16);
}

// __launch_bounds__(512, 2): the 2nd arg (min waves/EU) is the VGPR-cap control.
// R0 lesson: without it, the backend derives target occupancy from LDS (50 KiB ->
// 6 waves/EU -> 85-VGPR cap) and SPILLS the xr[64]/hr[64] arrays (VGPR_Count=76,
// 1012 us, VALUBusy 14%). With 2 waves/EU the cap is 256 VGPRs; 8-wave blocks
// need 2 waves/EU anyway, so occupancy is unchanged and the arrays stay in regs.
__global__ __launch_bounds__(512, 2) void k_mix(
    const float* __restrict__ X,  const float* __restrict__ W1,
    const float* __restrict__ B1, const float* __restrict__ W2,
    const float* __restrict__ B2, float* __restrict__ OUT,
    float* __restrict__ gsum, float* __restrict__ gsq)
{
    __shared__ __align__(16) unsigned char lds[50176];
    unsigned short* xs = (unsigned short*)lds;
    float* ssum = (float*)lds;                  // [64q][64b]
    float* ssq  = (float*)(lds + 16384);
    float* R    = (float*)(lds + 32768);        // [64b][68]

    const int tid  = threadIdx.x;
    const int lane = tid & 63;                       // batch lane
    const int wv   = __builtin_amdgcn_readfirstlane(tid >> 6);  // wave id -> channel (forced uniform)
    const int c0   = blockIdx.x * CT;
    const int b0   = blockIdx.y * BT;
    const int c    = c0 + wv;

    float xr[64];  // this thread's x[b0+lane, p, c] (bf16-rounded), later holds res[q]

    // ---- stage x through LDS transpose, two p-halves (keeps LDS small) ----
    #pragma unroll
    for (int ph = 0; ph < 2; ++ph) {
        // 4096 float4 quads: fi bits [0]=c4(2) [5:1]=p(32) [11:6]=b(64)
        // consecutive lanes cover 32 B contiguous (c4 fastest) -> L2 merges across
        // co-resident c-neighbor blocks (gridDim.x fastest = all c-groups per b-group)
        #pragma unroll
        for (int it = 0; it < 8; ++it) {
            int fi = it * 512 + tid;
            int c4 = fi & 1;
            int p  = (fi >> 1) & 31;
            int b  = fi >> 6;
            const float4 v = *(const float4*)(X + ((size_t)(b0 + b) * PP + (ph * 32 + p)) * CC + c0 + c4 * 4);
            int o0 = (c4 * 4) * (BT * 40) + b * 40 + p;
            xs[o0               ] = f2bf(v.x);
            xs[o0 + 1 * BT * 40 ] = f2bf(v.y);
            xs[o0 + 2 * BT * 40 ] = f2bf(v.z);
            xs[o0 + 3 * BT * 40 ] = f2bf(v.w);
        }
        __syncthreads();
        const unsigned short* row = xs + wv * (BT * 40) + lane * 40;
        #pragma unroll
        for (int i = 0; i < 32; ++i) xr[ph * 32 + i] = bf2f(row[i]);
        __syncthreads();   // before next half (or stats zeroing) overwrites region
    }

    // ---- zero LDS stats (region overlaps xs; xr regs already loaded) ----
    {
        float* z = (float*)lds;
        #pragma unroll
        for (int i = 0; i < 16; ++i) z[i * 512 + tid] = 0.0f;   // 8192 floats = ssum+ssq
    }
    __syncthreads();

    // Wave-uniform weight/bias pointers -> scalar-load candidates
    const float* __restrict__ w1c = W1 + (size_t)c * (PP * PP);
    const float* __restrict__ w2c = W2 + (size_t)c * (PP * PP);
    const float* __restrict__ b1c = B1 + (size_t)c * PP;
    const float* __restrict__ b2c = B2 + (size_t)c * PP;

    // ---- layer 1: h[q] = gelu( sum_p W1[c,q,p] * x[p] + b1[c,q] ) ----
    float hr[64];
    #pragma unroll
    for (int q = 0; q < 64; ++q) {
        float a0 = b1c[q], a1 = 0.f, a2 = 0.f, a3 = 0.f;  // 4 accs break dep chain
        #pragma unroll
        for (int p4 = 0; p4 < 16; ++p4) {
            const float4 w = *(const float4*)(w1c + q * 64 + p4 * 4);
            a0 += w.x * xr[p4 * 4 + 0];
            a1 += w.y * xr[p4 * 4 + 1];
            a2 += w.z * xr[p4 * 4 + 2];
            a3 += w.w * xr[p4 * 4 + 3];
        }
        float t = (a0 + a2) + (a1 + a3);
        // tanh-form GELU == t * sigmoid(2*0.79788456*(t + 0.044715 t^3));
        // max |dev| from exact erf-GELU ~3e-3 << 0.11 threshold
        float s = 1.5957691216f * (t + 0.044715f * t * t * t);
        hr[q] = t / (1.0f + __expf(-s));
    }

    // ---- layer 2 + residual + LN partial stats ----
    #pragma unroll
    for (int q = 0; q < 64; ++q) {
        float a0 = b2c[q], a1 = 0.f, a2 = 0.f, a3 = 0.f;
        #pragma unroll
        for (int p4 = 0; p4 < 16; ++p4) {
            const float4 w = *(const float4*)(w2c + q * 64 + p4 * 4);
            a0 += w.x * hr[p4 * 4 + 0];
            a1 += w.y * hr[p4 * 4 + 1];
            a2 += w.z * hr[p4 * 4 + 2];
            a3 += w.w * hr[p4 * 4 + 3];
        }
        float r = ((a0 + a2) + (a1 + a3)) + xr[q];
        xr[q] = r;                                   // xr[q] dead after residual -> reuse for res
        atomicAdd(&ssum[q * 64 + lane], r);          // ds_add_f32, 2-way bank alias = free
        atomicAdd(&ssq [q * 64 + lane], r * r);
    }
    __syncthreads();

    // ---- flush block-partial LN stats (8-ch partial per (b,q)) to global ----
    #pragma unroll
    for (int i = 0; i < 8; ++i) {
        int idx = i * 512 + tid;                     // 4096 (q,b) pairs
        int q = idx >> 6, b = idx & 63;
        int m = (b0 + b) * PP + q;
        atomicAdd(&gsum[m], ssum[idx]);
        atomicAdd(&gsq [m], ssq [idx]);
    }

    // ---- res write: stage through LDS -> 32 B-granule coalesced stores ----
    #pragma unroll
    for (int ch = 0; ch < 8; ++ch) {
        #pragma unroll
        for (int j = 0; j < 8; ++j)
            R[lane * 68 + j * 8 + wv] = xr[ch * 8 + j];
        __syncthreads();
        {
            int b = tid >> 3, jq = tid & 7;          // 512 (b,jq) pairs, 1 per thread
            const float4* src = (const float4*)(R + b * 68 + jq * 8);  // 16B aligned
            float4 v0 = src[0], v1 = src[1];
            size_t m = (size_t)(b0 + b) * PP + (ch * 8 + jq);
            float4* dst = (float4*)(OUT + m * CC + c0);
            dst[0] = v0; dst[1] = v1;
        }
        __syncthreads();   // before next chunk overwrites R
    }
}

// In-place LayerNorm over channels using the precomputed stats.
__global__ __launch_bounds__(256) void k_ln(
    float* __restrict__ OUT, const float* __restrict__ gsum, const float* __restrict__ gsq,
    const float* __restrict__ gamma, const float* __restrict__ beta)
{
    const int lane = threadIdx.x & 63;
    const int w    = threadIdx.x >> 6;
    const int m    = blockIdx.x * 4 + w;             // row over B*P = 65536
    float4* row = (float4*)(OUT + (size_t)m * CC);
    const float4* g4 = (const float4*)gamma;
    const float4* be4 = (const float4*)beta;
    float mu  = gsum[m] * (1.0f / CC);
    float var = gsq[m] * (1.0f / CC) - mu * mu;
    float inv = rsqrtf(var + LN_EPS);
    #pragma unroll
    for (int h = 0; h < 2; ++h) {
        int j = lane + h * 64;                       // 128 float4 per row
        float4 v = row[j], g = g4[j], bb = be4[j];
        v.x = (v.x - mu) * inv * g.x + bb.x;
        v.y = (v.y - mu) * inv * g.y + bb.y;
        v.z = (v.z - mu) * inv * g.z + bb.z;
        v.w = (v.w - mu) * inv * g.w + bb.w;
        row[j] = v;
    }
}

extern "C" void kernel_launch(void* const* d_in, const int* in_sizes, int n_in,
                              void* d_out, int out_size, void* d_ws, size_t ws_size,
                              hipStream_t stream) {
    const float* X  = (const float*)d_in[0];
    const float* W1 = (const float*)d_in[1];
    const float* B1 = (const float*)d_in[2];
    const float* W2 = (const float*)d_in[3];
    const float* B2 = (const float*)d_in[4];
    const float* G  = (const float*)d_in[5];
    const float* Be = (const float*)d_in[6];
    float* OUT  = (float*)d_out;
    float* gsum = (float*)d_ws;                      // [B*P] fp32
    float* gsq  = gsum + (size_t)BB * PP;            // [B*P] fp32  (512 KiB total in ws)

    hipMemsetAsync(d_ws, 0, (size_t)BB * PP * 2 * sizeof(float), stream);

    dim3 g1(CC / CT, BB / BT);                       // (64, 16): c-groups fastest -> co-resident for L2 merge
    k_mix<<<g1, 512, 0, stream>>>(X, W1, B1, W2, B2, OUT, gsum, gsq);
    k_ln<<<(BB * PP) / 4, 256, 0, stream>>>(OUT, gsum, gsq, G, Be);
}

// Round 3
// 366.705 us; speedup vs baseline: 3.3556x; 3.3556x over previous
//
#include <hip/hip_runtime.h>
#include <cstdint>
#include <cstddef>

// B=1024 batches, P=64 patches, C=512 channels. res = X + MLP_patch(X), then LN over C.
#define BB 1024
#define PP 64
#define CC 512
constexpr float LN_EPS = 1e-5f;

// MFMA fragment types (guide §3: short8 = 8 bf16 in 4 VGPRs, float4 acc)
typedef short  s16x8 __attribute__((ext_vector_type(8)));
typedef float  f32x4 __attribute__((ext_vector_type(4)));

__device__ __forceinline__ unsigned short f2bf(float f) {
    union { float f; unsigned u; } v; v.f = f;
    unsigned r = v.u + 0x7fffu + ((v.u >> 16) & 1u);   // RNE (finite inputs)
    return (unsigned short)(r >> 16);
}
__device__ __forceinline__ float bf2f(unsigned short h) {
    union { unsigned u; float f; } v; v.u = ((unsigned)h) << 16; return v.f;
}
// 8 consecutive fp32 -> bf16 B-fragment (all constant-index inserts: no alloca)
__device__ __forceinline__ s16x8 ldwf(const float* p) {
    float4 a = *(const float4*)p;
    float4 b = *(const float4*)(p + 4);
    s16x8 r;
    r[0] = (short)f2bf(a.x); r[1] = (short)f2bf(a.y);
    r[2] = (short)f2bf(a.z); r[3] = (short)f2bf(a.w);
    r[4] = (short)f2bf(b.x); r[5] = (short)f2bf(b.y);
    r[6] = (short)f2bf(b.z); r[7] = (short)f2bf(b.w);
    return r;
}

// Block: 256 threads = 4 waves; wave w owns channel c0+w; 128 batches in 8 subtiles of 16.
// R1 lesson: NO large per-thread arrays (SROA runs before unroll -> scratch). All MFMA
// state is named vector variables. (256,2): VGPR cap 256, 2 blocks/CU resident.
__global__ __launch_bounds__(256, 2) void k_mix(
    const float* __restrict__ X,  const float* __restrict__ W1,
    const float* __restrict__ B1, const float* __restrict__ W2,
    const float* __restrict__ B2, float* __restrict__ OUT)
{
    // XS/HS: bf16 [c-plane][b-local 16][p/q 64 pad->72] ; 72*2=144 B rows keep 16-B
    // alignment for ds_read_b128 and give 4-dword bank stagger.
    __shared__ __align__(16) unsigned short XS[4][16][72];   // 9216 B
    __shared__ __align__(16) unsigned short HS[4][16][72];   // 9216 B
    // RS: res staging fp32, flat [b][q*5 + c] with b-stride 321 (both strides odd-ish
    // mod 32 -> ~2-way max bank alias on scatter/gather).
    __shared__ float RS[16 * 321];                            // 20544 B

    const int tid   = threadIdx.x;
    const int lane  = tid & 63;
    const int wv    = tid >> 6;        // wave -> channel offset
    const int lrow  = lane & 15;       // MFMA m/n index
    const int lquad = lane >> 4;       // MFMA k-quad

    // XCD swizzle: gid&7 = XCD (round-robin heuristic, perf-only). Each XCD gets a
    // contiguous 64-channel range so the 16 B/line X reads/writes merge in its L2.
    const int gid  = blockIdx.x;
    const int xcd  = gid & 7, slot = gid >> 3;     // slot 0..127
    const int cg   = xcd * 16 + (slot & 15);       // 0..127 c-group (4 ch)
    const int bt   = slot >> 4;                    // 0..7 b-tile
    const int c0   = cg * 4, b0 = bt * 128;
    const int c    = c0 + wv;

    // ---- W1/W2 as B-fragments, resident in regs for the whole block ----
    // B[k=p][n=q]: lane n=q=nt*16+lrow, k=ks*32+lquad*8+j  -> 8 consecutive p of W[c,q,:]
    const float* w1c = W1 + (size_t)c * 4096;
    const float* w2c = W2 + (size_t)c * 4096;
    const int wq = lrow * 64 + lquad * 8;
    s16x8 w1_0_0 = ldwf(w1c +    0 + wq), w1_0_1 = ldwf(w1c +    0 + wq + 32);
    s16x8 w1_1_0 = ldwf(w1c + 1024 + wq), w1_1_1 = ldwf(w1c + 1024 + wq + 32);
    s16x8 w1_2_0 = ldwf(w1c + 2048 + wq), w1_2_1 = ldwf(w1c + 2048 + wq + 32);
    s16x8 w1_3_0 = ldwf(w1c + 3072 + wq), w1_3_1 = ldwf(w1c + 3072 + wq + 32);
    s16x8 w2_0_0 = ldwf(w2c +    0 + wq), w2_0_1 = ldwf(w2c +    0 + wq + 32);
    s16x8 w2_1_0 = ldwf(w2c + 1024 + wq), w2_1_1 = ldwf(w2c + 1024 + wq + 32);
    s16x8 w2_2_0 = ldwf(w2c + 2048 + wq), w2_2_1 = ldwf(w2c + 2048 + wq + 32);
    s16x8 w2_3_0 = ldwf(w2c + 3072 + wq), w2_3_1 = ldwf(w2c + 3072 + wq + 32);
    const float b1_0 = B1[c * 64 +  0 + lrow], b1_1 = B1[c * 64 + 16 + lrow];
    const float b1_2 = B1[c * 64 + 32 + lrow], b1_3 = B1[c * 64 + 48 + lrow];
    const float b2_0 = B2[c * 64 +  0 + lrow], b2_1 = B2[c * 64 + 16 + lrow];
    const float b2_2 = B2[c * 64 + 32 + lrow], b2_3 = B2[c * 64 + 48 + lrow];

    const unsigned short* xp = &XS[wv][0][0];
    unsigned short*       hp = &HS[wv][0][0];

    for (int s = 0; s < 8; ++s) {
        const int bb = b0 + s * 16;

        // ---- stage X[bb..bb+15][0..63][c0..c0+3] -> XS bf16 (transpose) ----
        #pragma unroll
        for (int it = 0; it < 2; ++it) {
            int pi = it * 256 + tid;          // 512 (b,p-pair) units
            int b = pi >> 5, p2 = pi & 31;
            const float* src = X + ((size_t)(bb + b) * PP + 2 * p2) * CC + c0;
            const float4 v0 = *(const float4*)src;
            const float4 v1 = *(const float4*)(src + CC);
            *(unsigned*)&XS[0][b][2 * p2] = (unsigned)f2bf(v0.x) | ((unsigned)f2bf(v1.x) << 16);
            *(unsigned*)&XS[1][b][2 * p2] = (unsigned)f2bf(v0.y) | ((unsigned)f2bf(v1.y) << 16);
            *(unsigned*)&XS[2][b][2 * p2] = (unsigned)f2bf(v0.z) | ((unsigned)f2bf(v1.z) << 16);
            *(unsigned*)&XS[3][b][2 * p2] = (unsigned)f2bf(v0.w) | ((unsigned)f2bf(v1.w) << 16);
        }
        __syncthreads();

        // ---- A-fragments of X: A[m=lrow][k=lquad*8+j (+32*ks)] ----
        s16x8 af0 = *(const s16x8*)(xp + lrow * 72 +  0 + lquad * 8);
        s16x8 af1 = *(const s16x8*)(xp + lrow * 72 + 32 + lquad * 8);

        // ---- GEMM1 (K=64) + bias + GELU -> HS (C-layout: row=b=lquad*4+r, col=q) ----
        #define DO1(nt) { \
            f32x4 a = {b1_##nt, b1_##nt, b1_##nt, b1_##nt}; \
            a = __builtin_amdgcn_mfma_f32_16x16x32_bf16(af0, w1_##nt##_0, a, 0, 0, 0); \
            a = __builtin_amdgcn_mfma_f32_16x16x32_bf16(af1, w1_##nt##_1, a, 0, 0, 0); \
            _Pragma("unroll") for (int r = 0; r < 4; ++r) { \
                float t = a[r]; \
                float sg = 1.5957691216f * (t + 0.044715f * t * t * t); \
                float h = t / (1.0f + __expf(-sg)); \
                hp[(lquad * 4 + r) * 72 + (nt * 16 + lrow)] = f2bf(h); \
            } }
        DO1(0) DO1(1) DO1(2) DO1(3)
        #undef DO1
        __syncthreads();   // cross-lane H handoff within wave (keep compiler honest too)

        // ---- A-fragments of H ----
        s16x8 hf0 = *(const s16x8*)(hp + lrow * 72 +  0 + lquad * 8);
        s16x8 hf1 = *(const s16x8*)(hp + lrow * 72 + 32 + lquad * 8);

        // ---- GEMM2 + bias + residual -> RS ----
        #define DO2(nt) { \
            f32x4 a = {b2_##nt, b2_##nt, b2_##nt, b2_##nt}; \
            a = __builtin_amdgcn_mfma_f32_16x16x32_bf16(hf0, w2_##nt##_0, a, 0, 0, 0); \
            a = __builtin_amdgcn_mfma_f32_16x16x32_bf16(hf1, w2_##nt##_1, a, 0, 0, 0); \
            _Pragma("unroll") for (int r = 0; r < 4; ++r) { \
                int b = lquad * 4 + r, q = nt * 16 + lrow; \
                float res = a[r] + bf2f(xp[b * 72 + q]); \
                RS[b * 321 + q * 5 + wv] = res; \
            } }
        DO2(0) DO2(1) DO2(2) DO2(3)
        #undef DO2
        __syncthreads();

        // ---- gather RS -> 16 B-granule stores (L2 merges neighbors via XCD swizzle) ----
        #pragma unroll
        for (int it = 0; it < 4; ++it) {
            int fi = it * 256 + tid;          // 1024 (b,q) rows
            int q = fi & 63, b = fi >> 6;
            const float* rp = RS + b * 321 + q * 5;
            float4 v = { rp[0], rp[1], rp[2], rp[3] };
            *(float4*)(OUT + ((size_t)(bb + b) * PP + q) * CC + c0) = v;
        }
        __syncthreads();   // RS reads done before next subtile's writes
    }
}

// LayerNorm over channels: one wave per (b,p) row (512 ch = 64 lanes x 2 float4).
// Pure shuffle reduction: no LDS, no atomics, no stats kernel.
__global__ __launch_bounds__(256) void k_ln(
    float* __restrict__ OUT, const float* __restrict__ G, const float* __restrict__ Be)
{
    const int lane = threadIdx.x & 63;
    const int m    = blockIdx.x * 4 + (threadIdx.x >> 6);
    float4* row = (float4*)(OUT + (size_t)m * CC);
    float4 v0 = row[lane], v1 = row[lane + 64];
    float s = (v0.x + v0.y) + (v0.z + v0.w) + (v1.x + v1.y) + (v1.z + v1.w);
    float q = (v0.x * v0.x + v0.y * v0.y) + (v0.z * v0.z + v0.w * v0.w)
            + (v1.x * v1.x + v1.y * v1.y) + (v1.z * v1.z + v1.w * v1.w);
    #pragma unroll
    for (int o = 32; o >= 1; o >>= 1) {
        s += __shfl_xor(s, o, 64);
        q += __shfl_xor(q, o, 64);
    }
    const float mu  = s * (1.0f / CC);
    const float var = q * (1.0f / CC) - mu * mu;
    const float inv = rsqrtf(var + LN_EPS);
    const float4 g0 = ((const float4*)G)[lane],  g1 = ((const float4*)G)[lane + 64];
    const float4 e0 = ((const float4*)Be)[lane], e1 = ((const float4*)Be)[lane + 64];
    v0.x = (v0.x - mu) * inv * g0.x + e0.x;  v0.y = (v0.y - mu) * inv * g0.y + e0.y;
    v0.z = (v0.z - mu) * inv * g0.z + e0.z;  v0.w = (v0.w - mu) * inv * g0.w + e0.w;
    v1.x = (v1.x - mu) * inv * g1.x + e1.x;  v1.y = (v1.y - mu) * inv * g1.y + e1.y;
    v1.z = (v1.z - mu) * inv * g1.z + e1.z;  v1.w = (v1.w - mu) * inv * g1.w + e1.w;
    row[lane] = v0; row[lane + 64] = v1;
}

extern "C" void kernel_launch(void* const* d_in, const int* in_sizes, int n_in,
                              void* d_out, int out_size, void* d_ws, size_t ws_size,
                              hipStream_t stream) {
    const float* X  = (const float*)d_in[0];
    const float* W1 = (const float*)d_in[1];
    const float* B1 = (const float*)d_in[2];
    const float* W2 = (const float*)d_in[3];
    const float* B2 = (const float*)d_in[4];
    const float* G  = (const float*)d_in[5];
    const float* Be = (const float*)d_in[6];
    float* OUT = (float*)d_out;

    k_mix<<<1024, 256, 0, stream>>>(X, W1, B1, W2, B2, OUT);       // 128 c-grp x 8 b-tile
    k_ln<<<(BB * PP) / 4, 256, 0, stream>>>(OUT, G, Be);           // 65536 rows / 4
}